// Round 11
// baseline (1104.599 us; speedup 1.0000x reference)
//
#include <hip/hip_runtime.h>
#include <hip/hip_bf16.h>

#define N_PTS 800000
#define KVOL 27
#define NPAIR 14        // 27 taps -> 14 pairs (tap 27 = zero pad)
#define NHEADS 4
#define NT (N_PTS / 16) // 50000 16-point tiles
#define WPK_ELEMS (NPAIR * NHEADS * 64 * 8)   // 28672 shorts = 57344 B
#define NBLK 512        // persistent: 2 blocks/CU x 256 CU
#define NWAVE (NBLK * 16)

typedef __attribute__((ext_vector_type(8))) short short8;
typedef __attribute__((ext_vector_type(4))) float f32x4;

__device__ inline short f2bf(float x) {
    __hip_bfloat16 h = __float2bfloat16(x);
    short s;
    __builtin_memcpy(&s, &h, 2);
    return s;
}

// ------------- pre-pass 1: fp32 feats -> bf16 feats (+1 zero row) in d_ws -------------
__global__ __launch_bounds__(256) void cvt_bf16(const float* __restrict__ in,
                                                short* __restrict__ outp) {
    const size_t n8_data = (size_t)N_PTS * 8;
    const size_t n8_all  = (size_t)(N_PTS + 1) * 8;
    const size_t stride  = (size_t)gridDim.x * 256;
    for (size_t k = (size_t)blockIdx.x * 256 + threadIdx.x; k < n8_all; k += stride) {
        short8 o = {0,0,0,0,0,0,0,0};
        if (k < n8_data) {
            const float4 x0 = ((const float4*)in)[k * 2];
            const float4 x1 = ((const float4*)in)[k * 2 + 1];
            o = (short8){f2bf(x0.x), f2bf(x0.y), f2bf(x0.z), f2bf(x0.w),
                         f2bf(x1.x), f2bf(x1.y), f2bf(x1.z), f2bf(x1.w)};
        }
        ((short8*)outp)[k] = o;
    }
}

// ------------- pre-pass 2: pack weights into the exact LDS fragment image -------------
__global__ __launch_bounds__(1024) void pack_w(const float* __restrict__ W,
                                               short* __restrict__ wpk) {
    const int e = blockIdx.x * 1024 + threadIdx.x;
    if (e >= WPK_ELEMS) return;
    const int j   = e & 7;
    const int ln  = (e >> 3) & 63;
    const int h   = (e >> 9) & 3;
    const int t   = e >> 11;
    const int gg2 = ln >> 4;
    const int d   = ln & 15;
    const int klw = gg2 >> 1;
    const int c   = ((gg2 & 1) << 3) + j;
    const int tap = 2 * t + klw;
    const float w = (tap < KVOL) ? W[((tap * NHEADS + h) * 16 + c) * 16 + d] : 0.0f;
    wpk[e] = f2bf(w);
}

// ------- main: persistent blocks, exec-masked gathers, depth-2 pipeline -------
// Round-10 champion structure + two changes:
//  (1) persistent 512 blocks (2/CU): LDS prologue once per block (was 6.1x per
//      CU-slot timeline) and no ragged dispatch tail;
//  (2) exec-masked gathers: ~87% of (point,tap) taps are invalid; previously
//      their lanes issued real loads of the shared zero row (~2.4 GB of L1
//      traffic occupying the vector-memory path). Pre-zero the named buffer
//      regs and issue the 4 loads under if(idx>=0): invalid lanes generate NO
//      transactions; pipeline shape (issue GATH t+2 before MST t) unchanged.
// Spill check stays: WRITE_SIZE must be exactly 200 MB.
__global__ __launch_bounds__(1024)
__attribute__((amdgpu_waves_per_eu(8, 8)))
void mh_conv_bf(
        const short* __restrict__ bfeats,   // [N+1][64] bf16 (row N = zeros)
        const short* __restrict__ wpk,      // [WPK_ELEMS] prepacked B fragments
        const int*   __restrict__ kmap,     // [27][N]
        float*       __restrict__ out) {    // [N][64]

    // ---- stage prepacked B fragments into LDS: linear 57KB vector copy ----
    __shared__ short bsh[WPK_ELEMS];   // 57344 B
    const int tid = threadIdx.x;
    {
        const short8* wp8  = (const short8*)wpk;
        short8*       bs8w = (short8*)bsh;
        #pragma unroll
        for (int e = tid; e < WPK_ELEMS / 8; e += 1024)
            bs8w[e] = wp8[e];
    }
    __syncthreads();

    const int lane = tid & 63;
    const int wid  = tid >> 6;             // 0..15
    const int m    = lane & 15;            // point row within tile
    const int gg   = lane >> 4;            // lane group 0..3
    const int kl   = gg >> 1;              // tap-within-pair (0/1)
    const int half = gg & 1;               // 8-ch chunk within each head

    const short8* bf8  = (const short8*)bfeats;
    const short8* bsh8 = (const short8*)bsh;
    const short8 z8 = {0,0,0,0,0,0,0,0};

// kmap load for pair t (tap 2t+kl); pad tap (27) -> -1 (t is compile-time const)
#define LDIX(v, t)                                                               \
    do {                                                                         \
        const int tap_ = 2 * (t) + kl;                                           \
        const int sat_ = (tap_ < KVOL) ? tap_ : (KVOL - 1);                      \
        const int u_   = kmap[(size_t)sat_ * N_PTS + p];                         \
        (v) = (tap_ < KVOL) ? u_ : -1;                                           \
    } while (0);

// exec-masked gather: pre-zero named regs, load only in valid lanes
#define GATH(P, i)                                                               \
    {                                                                            \
        P##0 = z8; P##1 = z8; P##2 = z8; P##3 = z8;                              \
        if ((i) >= 0) {                                                          \
            const short8* fr_ = bf8 + (size_t)(i) * 8 + half;                    \
            P##0 = fr_[0]; P##1 = fr_[2]; P##2 = fr_[4]; P##3 = fr_[6];          \
        }                                                                        \
    }

// 4 MFMAs (one per head) consuming buffer set P against LDS B fragments of pair t
#define MST(t, P)                                                                \
    {                                                                            \
        const short8* bp_ = bsh8 + ((t) * 4 * 64 + lane);                        \
        acc0 = __builtin_amdgcn_mfma_f32_16x16x32_bf16(P##0, bp_[0],   acc0, 0, 0, 0); \
        acc1 = __builtin_amdgcn_mfma_f32_16x16x32_bf16(P##1, bp_[64],  acc1, 0, 0, 0); \
        acc2 = __builtin_amdgcn_mfma_f32_16x16x32_bf16(P##2, bp_[128], acc2, 0, 0, 0); \
        acc3 = __builtin_amdgcn_mfma_f32_16x16x32_bf16(P##3, bp_[192], acc3, 0, 0, 0); \
    }

    // ---- persistent wave loop: ~6 tiles per wave, no barriers inside ----
    for (int tile = blockIdx.x * 16 + wid; tile < NT; tile += NWAVE) {
        const int p = tile * 16 + m;

        f32x4 acc0 = {0.f,0.f,0.f,0.f};
        f32x4 acc1 = {0.f,0.f,0.f,0.f};
        f32x4 acc2 = {0.f,0.f,0.f,0.f};
        f32x4 acc3 = {0.f,0.f,0.f,0.f};

        // ---- depth-2 pipeline: 2 buffer sets (A,B), 2 rolling index regs ----
        short8 A0,A1,A2,A3, B0,B1,B2,B3;
        int ia, ib;
        LDIX(ia, 0)
        LDIX(ib, 1)
        GATH(A, ia)  LDIX(ia, 2)
        GATH(B, ib)  LDIX(ib, 3)
        MST(0, A)    GATH(A, ia)  LDIX(ia, 4)
        MST(1, B)    GATH(B, ib)  LDIX(ib, 5)
        MST(2, A)    GATH(A, ia)  LDIX(ia, 6)
        MST(3, B)    GATH(B, ib)  LDIX(ib, 7)
        MST(4, A)    GATH(A, ia)  LDIX(ia, 8)
        MST(5, B)    GATH(B, ib)  LDIX(ib, 9)
        MST(6, A)    GATH(A, ia)  LDIX(ia, 10)
        MST(7, B)    GATH(B, ib)  LDIX(ib, 11)
        MST(8, A)    GATH(A, ia)  LDIX(ia, 12)
        MST(9, B)    GATH(B, ib)  LDIX(ib, 13)
        MST(10, A)   GATH(A, ia)
        MST(11, B)   GATH(B, ib)
        MST(12, A)
        MST(13, B)

        // ---- store: D layout col = lane&15, row = gg*4 + r ----
        const int col = lane & 15;
        const int r0  = tile * 16 + gg * 4;
        #pragma unroll
        for (int r = 0; r < 4; ++r) {
            const size_t ro = (size_t)(r0 + r) * 64;
            out[ro +  0 + col] = acc0[r];
            out[ro + 16 + col] = acc1[r];
            out[ro + 32 + col] = acc2[r];
            out[ro + 48 + col] = acc3[r];
        }
    }
#undef LDIX
#undef GATH
#undef MST
}

// ------------- fallback (ws too small): round-1 kernel, known-good -------------
__global__ __launch_bounds__(512, 4) void mh_conv_fp32(
        const float* __restrict__ feats, const float* __restrict__ W,
        const int* __restrict__ kmap, float* __restrict__ out) {
    __shared__ short bsh[NPAIR * NHEADS * 64 * 8];
    const int tid = threadIdx.x;
    for (int e = tid; e < NPAIR * NHEADS * 64 * 8; e += 512) {
        const int j = e & 7, ln = (e >> 3) & 63, h = (e >> 9) & 3, t = e >> 11;
        const int gg = ln >> 4, d = ln & 15, klw = gg >> 1, c = ((gg & 1) << 3) + j;
        const int tap = 2 * t + klw;
        const float w = (tap < KVOL) ? W[((tap * NHEADS + h) * 16 + c) * 16 + d] : 0.0f;
        bsh[e] = f2bf(w);
    }
    __syncthreads();
    const int lane = tid & 63, wid = tid >> 6;
    const int m = lane & 15, gg = lane >> 4, kl = gg >> 1, ch = (gg & 1) << 3;
    const int gw = blockIdx.x * 8 + wid, nw = gridDim.x * 8;
    for (int tile = gw; tile < NT; tile += nw) {
        const int p = tile * 16 + m;
        f32x4 acc0 = {0,0,0,0}, acc1 = {0,0,0,0}, acc2 = {0,0,0,0}, acc3 = {0,0,0,0};
        #pragma unroll
        for (int t = 0; t < NPAIR; ++t) {
            const int tap = 2 * t + kl;
            int idx = -1;
            if (tap < KVOL) idx = kmap[(size_t)tap * N_PTS + p];
            if (__ballot(idx >= 0)) {
                short8 a0 = {0,0,0,0,0,0,0,0}, a1 = a0, a2 = a0, a3 = a0;
                if (idx >= 0) {
                    const float* fr = feats + (size_t)idx * 64 + ch;
                    const float4 x0 = *(const float4*)(fr +  0);
                    const float4 x1 = *(const float4*)(fr +  4);
                    const float4 x2 = *(const float4*)(fr + 16);
                    const float4 x3 = *(const float4*)(fr + 20);
                    const float4 x4 = *(const float4*)(fr + 32);
                    const float4 x5 = *(const float4*)(fr + 36);
                    const float4 x6 = *(const float4*)(fr + 48);
                    const float4 x7 = *(const float4*)(fr + 52);
                    a0 = (short8){f2bf(x0.x),f2bf(x0.y),f2bf(x0.z),f2bf(x0.w),
                                  f2bf(x1.x),f2bf(x1.y),f2bf(x1.z),f2bf(x1.w)};
                    a1 = (short8){f2bf(x2.x),f2bf(x2.y),f2bf(x2.z),f2bf(x2.w),
                                  f2bf(x3.x),f2bf(x3.y),f2bf(x3.z),f2bf(x3.w)};
                    a2 = (short8){f2bf(x4.x),f2bf(x4.y),f2bf(x4.z),f2bf(x4.w),
                                  f2bf(x5.x),f2bf(x5.y),f2bf(x5.z),f2bf(x5.w)};
                    a3 = (short8){f2bf(x6.x),f2bf(x6.y),f2bf(x6.z),f2bf(x6.w),
                                  f2bf(x7.x),f2bf(x7.y),f2bf(x7.z),f2bf(x7.w)};
                }
                const short8* bp = (const short8*)(bsh + ((size_t)t * 4 * 64 + lane) * 8);
                acc0 = __builtin_amdgcn_mfma_f32_16x16x32_bf16(a0, bp[0],   acc0, 0, 0, 0);
                acc1 = __builtin_amdgcn_mfma_f32_16x16x32_bf16(a1, bp[64],  acc1, 0, 0, 0);
                acc2 = __builtin_amdgcn_mfma_f32_16x16x32_bf16(a2, bp[128], acc2, 0, 0, 0);
                acc3 = __builtin_amdgcn_mfma_f32_16x16x32_bf16(a3, bp[192], acc3, 0, 0, 0);
            }
        }
        const int col = lane & 15;
        const int r0 = tile * 16 + (lane >> 4) * 4;
        #pragma unroll
        for (int r = 0; r < 4; ++r) {
            const size_t ro = (size_t)(r0 + r) * 64;
            out[ro +  0 + col] = acc0[r];
            out[ro + 16 + col] = acc1[r];
            out[ro + 32 + col] = acc2[r];
            out[ro + 48 + col] = acc3[r];
        }
    }
}

extern "C" void kernel_launch(void* const* d_in, const int* in_sizes, int n_in,
                              void* d_out, int out_size, void* d_ws, size_t ws_size,
                              hipStream_t stream) {
    const float* feats = (const float*)d_in[0];
    const float* W     = (const float*)d_in[1];
    const int*   kmap  = (const int*)d_in[2];
    float*       out   = (float*)d_out;

    const size_t bf_bytes = (size_t)(N_PTS + 1) * 64 * 2;      // 102,400,128 B (16B-aligned)
    const size_t need     = bf_bytes + (size_t)WPK_ELEMS * 2;  // + 57,344 B packed weights
    if (ws_size >= need) {
        short* bfeats = (short*)d_ws;
        short* wpk    = (short*)((char*)d_ws + bf_bytes);
        hipLaunchKernelGGL(cvt_bf16, dim3(4096), dim3(256), 0, stream, feats, bfeats);
        hipLaunchKernelGGL(pack_w, dim3((WPK_ELEMS + 1023) / 1024), dim3(1024), 0, stream,
                           W, wpk);
        hipLaunchKernelGGL(mh_conv_bf, dim3(NBLK), dim3(1024), 0, stream,
                           bfeats, wpk, kmap, out);
    } else {
        hipLaunchKernelGGL(mh_conv_fp32, dim3(1024), dim3(512), 0, stream,
                           feats, W, kmap, out);
    }
}

// Round 12
// 233.631 us; speedup vs baseline: 4.7280x; 4.7280x over previous
//
#include <hip/hip_runtime.h>
#include <hip/hip_bf16.h>

#define N_PTS 800000
#define KVOL 27
#define NPAIR 14        // 27 taps -> 14 pairs (tap 27 = zero pad)
#define NHEADS 4
#define NT (N_PTS / 16) // 50000 16-point tiles
#define WPK_ELEMS (NPAIR * NHEADS * 64 * 8)   // 28672 shorts = 57344 B

typedef __attribute__((ext_vector_type(8))) short short8;
typedef __attribute__((ext_vector_type(4))) float f32x4;

__device__ inline short f2bf(float x) {
    __hip_bfloat16 h = __float2bfloat16(x);
    short s;
    __builtin_memcpy(&s, &h, 2);
    return s;
}

// ------------- pre-pass 1: fp32 feats -> bf16 feats (+1 zero row) in d_ws -------------
__global__ __launch_bounds__(256) void cvt_bf16(const float* __restrict__ in,
                                                short* __restrict__ outp) {
    const size_t n8_data = (size_t)N_PTS * 8;
    const size_t n8_all  = (size_t)(N_PTS + 1) * 8;
    const size_t stride  = (size_t)gridDim.x * 256;
    for (size_t k = (size_t)blockIdx.x * 256 + threadIdx.x; k < n8_all; k += stride) {
        short8 o = {0,0,0,0,0,0,0,0};
        if (k < n8_data) {
            const float4 x0 = ((const float4*)in)[k * 2];
            const float4 x1 = ((const float4*)in)[k * 2 + 1];
            o = (short8){f2bf(x0.x), f2bf(x0.y), f2bf(x0.z), f2bf(x0.w),
                         f2bf(x1.x), f2bf(x1.y), f2bf(x1.z), f2bf(x1.w)};
        }
        ((short8*)outp)[k] = o;
    }
}

// ------------- pre-pass 2: pack weights into the exact LDS fragment image -------------
__global__ __launch_bounds__(1024) void pack_w(const float* __restrict__ W,
                                               short* __restrict__ wpk) {
    const int e = blockIdx.x * 1024 + threadIdx.x;
    if (e >= WPK_ELEMS) return;
    const int j   = e & 7;
    const int ln  = (e >> 3) & 63;
    const int h   = (e >> 9) & 3;
    const int t   = e >> 11;
    const int gg2 = ln >> 4;
    const int d   = ln & 15;
    const int klw = gg2 >> 1;
    const int c   = ((gg2 & 1) << 3) + j;
    const int tap = 2 * t + klw;
    const float w = (tap < KVOL) ? W[((tap * NHEADS + h) * 16 + c) * 16 + d] : 0.0f;
    wpk[e] = f2bf(w);
}

// ------- main: ROUND-10 CHAMPION (190us) + nontemporal out-stores / kmap-loads -------
// Structure frozen: block=1024 (16 waves), 3125 blocks, LDS 57344 B -> 2 blocks/CU
// -> 32 waves/CU; waves_per_eu(8,8) = 64-reg budget which depth-2 exactly fills
// (zero spill; WRITE_SIZE must stay exactly 200 MB). Round-11 lesson: gathers must
// be UNCONDITIONAL straight-line loads (masking only in the address select);
// divergent-branch-guarded pipelined loads -> spill catastrophe.
// This round's single change: nontemporal hints on the 200MB output stream and
// 86MB kmap stream so write-allocate/stream data stops evicting the bfeats gather
// working set (102MB unique + ~266MB L3-served reuse) from L2/L3.
__global__ __launch_bounds__(1024)
__attribute__((amdgpu_waves_per_eu(8, 8)))
void mh_conv_bf(
        const short* __restrict__ bfeats,   // [N+1][64] bf16 (row N = zeros)
        const short* __restrict__ wpk,      // [WPK_ELEMS] prepacked B fragments
        const int*   __restrict__ kmap,     // [27][N]
        float*       __restrict__ out) {    // [N][64]

    // ---- stage prepacked B fragments into LDS: linear 57KB vector copy ----
    __shared__ short bsh[WPK_ELEMS];   // 57344 B
    const int tid = threadIdx.x;
    {
        const short8* wp8  = (const short8*)wpk;
        short8*       bs8w = (short8*)bsh;
        #pragma unroll
        for (int e = tid; e < WPK_ELEMS / 8; e += 1024)
            bs8w[e] = wp8[e];
    }
    __syncthreads();

    const int lane = tid & 63;
    const int wid  = tid >> 6;             // 0..15
    const int m    = lane & 15;            // point row within tile
    const int gg   = lane >> 4;            // lane group 0..3
    const int kl   = gg >> 1;              // tap-within-pair (0/1)
    const int half = gg & 1;               // 8-ch chunk within each head
    const int tile = blockIdx.x * 16 + wid; // one 16-point tile per wave
    const int p    = tile * 16 + m;

    const short8* bf8  = (const short8*)bfeats;
    const short8* bsh8 = (const short8*)bsh;

// kmap load for pair t (tap 2t+kl); pad tap (27) -> -1; nontemporal (streamed once)
#define LDIX(v, t)                                                               \
    do {                                                                         \
        const int tap_ = 2 * (t) + kl;                                           \
        const int sat_ = (tap_ < KVOL) ? tap_ : (KVOL - 1);                      \
        const int u_   = __builtin_nontemporal_load(&kmap[(size_t)sat_ * N_PTS + p]); \
        (v) = (tap_ < KVOL) ? u_ : -1;                                           \
    } while (0);

// issue 4 unconditional 16B gathers into named buffer set P (P##0..P##3)
#define GATH(P, i)                                                               \
    {                                                                            \
        const int si_ = ((i) >= 0) ? (i) : N_PTS;                                \
        const short8* fr_ = bf8 + (size_t)si_ * 8 + half;                        \
        P##0 = fr_[0]; P##1 = fr_[2]; P##2 = fr_[4]; P##3 = fr_[6];              \
    }

// 4 MFMAs (one per head) consuming buffer set P against LDS B fragments of pair t
#define MST(t, P)                                                                \
    {                                                                            \
        const short8* bp_ = bsh8 + ((t) * 4 * 64 + lane);                        \
        acc0 = __builtin_amdgcn_mfma_f32_16x16x32_bf16(P##0, bp_[0],   acc0, 0, 0, 0); \
        acc1 = __builtin_amdgcn_mfma_f32_16x16x32_bf16(P##1, bp_[64],  acc1, 0, 0, 0); \
        acc2 = __builtin_amdgcn_mfma_f32_16x16x32_bf16(P##2, bp_[128], acc2, 0, 0, 0); \
        acc3 = __builtin_amdgcn_mfma_f32_16x16x32_bf16(P##3, bp_[192], acc3, 0, 0, 0); \
    }

    f32x4 acc0 = {0.f,0.f,0.f,0.f};
    f32x4 acc1 = {0.f,0.f,0.f,0.f};
    f32x4 acc2 = {0.f,0.f,0.f,0.f};
    f32x4 acc3 = {0.f,0.f,0.f,0.f};

    // ---- depth-2 pipeline: 2 buffer sets (A,B), 2 rolling index regs ----
    short8 A0,A1,A2,A3, B0,B1,B2,B3;
    int ia, ib;
    LDIX(ia, 0)
    LDIX(ib, 1)
    GATH(A, ia)  LDIX(ia, 2)
    GATH(B, ib)  LDIX(ib, 3)
    MST(0, A)    GATH(A, ia)  LDIX(ia, 4)
    MST(1, B)    GATH(B, ib)  LDIX(ib, 5)
    MST(2, A)    GATH(A, ia)  LDIX(ia, 6)
    MST(3, B)    GATH(B, ib)  LDIX(ib, 7)
    MST(4, A)    GATH(A, ia)  LDIX(ia, 8)
    MST(5, B)    GATH(B, ib)  LDIX(ib, 9)
    MST(6, A)    GATH(A, ia)  LDIX(ia, 10)
    MST(7, B)    GATH(B, ib)  LDIX(ib, 11)
    MST(8, A)    GATH(A, ia)  LDIX(ia, 12)
    MST(9, B)    GATH(B, ib)  LDIX(ib, 13)
    MST(10, A)   GATH(A, ia)
    MST(11, B)   GATH(B, ib)
    MST(12, A)
    MST(13, B)

    // ---- store: D layout col = lane&15, row = gg*4 + r; nontemporal (write-only) ----
    const int col = lane & 15;
    const int r0  = tile * 16 + gg * 4;
    #pragma unroll
    for (int r = 0; r < 4; ++r) {
        const size_t ro = (size_t)(r0 + r) * 64;
        __builtin_nontemporal_store(acc0[r], &out[ro +  0 + col]);
        __builtin_nontemporal_store(acc1[r], &out[ro + 16 + col]);
        __builtin_nontemporal_store(acc2[r], &out[ro + 32 + col]);
        __builtin_nontemporal_store(acc3[r], &out[ro + 48 + col]);
    }
#undef LDIX
#undef GATH
#undef MST
}

// ------------- fallback (ws too small): round-1 kernel, known-good -------------
__global__ __launch_bounds__(512, 4) void mh_conv_fp32(
        const float* __restrict__ feats, const float* __restrict__ W,
        const int* __restrict__ kmap, float* __restrict__ out) {
    __shared__ short bsh[NPAIR * NHEADS * 64 * 8];
    const int tid = threadIdx.x;
    for (int e = tid; e < NPAIR * NHEADS * 64 * 8; e += 512) {
        const int j = e & 7, ln = (e >> 3) & 63, h = (e >> 9) & 3, t = e >> 11;
        const int gg = ln >> 4, d = ln & 15, klw = gg >> 1, c = ((gg & 1) << 3) + j;
        const int tap = 2 * t + klw;
        const float w = (tap < KVOL) ? W[((tap * NHEADS + h) * 16 + c) * 16 + d] : 0.0f;
        bsh[e] = f2bf(w);
    }
    __syncthreads();
    const int lane = tid & 63, wid = tid >> 6;
    const int m = lane & 15, gg = lane >> 4, kl = gg >> 1, ch = (gg & 1) << 3;
    const int gw = blockIdx.x * 8 + wid, nw = gridDim.x * 8;
    for (int tile = gw; tile < NT; tile += nw) {
        const int p = tile * 16 + m;
        f32x4 acc0 = {0,0,0,0}, acc1 = {0,0,0,0}, acc2 = {0,0,0,0}, acc3 = {0,0,0,0};
        #pragma unroll
        for (int t = 0; t < NPAIR; ++t) {
            const int tap = 2 * t + kl;
            int idx = -1;
            if (tap < KVOL) idx = kmap[(size_t)tap * N_PTS + p];
            if (__ballot(idx >= 0)) {
                short8 a0 = {0,0,0,0,0,0,0,0}, a1 = a0, a2 = a0, a3 = a0;
                if (idx >= 0) {
                    const float* fr = feats + (size_t)idx * 64 + ch;
                    const float4 x0 = *(const float4*)(fr +  0);
                    const float4 x1 = *(const float4*)(fr +  4);
                    const float4 x2 = *(const float4*)(fr + 16);
                    const float4 x3 = *(const float4*)(fr + 20);
                    const float4 x4 = *(const float4*)(fr + 32);
                    const float4 x5 = *(const float4*)(fr + 36);
                    const float4 x6 = *(const float4*)(fr + 48);
                    const float4 x7 = *(const float4*)(fr + 52);
                    a0 = (short8){f2bf(x0.x),f2bf(x0.y),f2bf(x0.z),f2bf(x0.w),
                                  f2bf(x1.x),f2bf(x1.y),f2bf(x1.z),f2bf(x1.w)};
                    a1 = (short8){f2bf(x2.x),f2bf(x2.y),f2bf(x2.z),f2bf(x2.w),
                                  f2bf(x3.x),f2bf(x3.y),f2bf(x3.z),f2bf(x3.w)};
                    a2 = (short8){f2bf(x4.x),f2bf(x4.y),f2bf(x4.z),f2bf(x4.w),
                                  f2bf(x5.x),f2bf(x5.y),f2bf(x5.z),f2bf(x5.w)};
                    a3 = (short8){f2bf(x6.x),f2bf(x6.y),f2bf(x6.z),f2bf(x6.w),
                                  f2bf(x7.x),f2bf(x7.y),f2bf(x7.z),f2bf(x7.w)};
                }
                const short8* bp = (const short8*)(bsh + ((size_t)t * 4 * 64 + lane) * 8);
                acc0 = __builtin_amdgcn_mfma_f32_16x16x32_bf16(a0, bp[0],   acc0, 0, 0, 0);
                acc1 = __builtin_amdgcn_mfma_f32_16x16x32_bf16(a1, bp[64],  acc1, 0, 0, 0);
                acc2 = __builtin_amdgcn_mfma_f32_16x16x32_bf16(a2, bp[128], acc2, 0, 0, 0);
                acc3 = __builtin_amdgcn_mfma_f32_16x16x32_bf16(a3, bp[192], acc3, 0, 0, 0);
            }
        }
        const int col = lane & 15;
        const int r0 = tile * 16 + (lane >> 4) * 4;
        #pragma unroll
        for (int r = 0; r < 4; ++r) {
            const size_t ro = (size_t)(r0 + r) * 64;
            out[ro +  0 + col] = acc0[r];
            out[ro + 16 + col] = acc1[r];
            out[ro + 32 + col] = acc2[r];
            out[ro + 48 + col] = acc3[r];
        }
    }
}

extern "C" void kernel_launch(void* const* d_in, const int* in_sizes, int n_in,
                              void* d_out, int out_size, void* d_ws, size_t ws_size,
                              hipStream_t stream) {
    const float* feats = (const float*)d_in[0];
    const float* W     = (const float*)d_in[1];
    const int*   kmap  = (const int*)d_in[2];
    float*       out   = (float*)d_out;

    const size_t bf_bytes = (size_t)(N_PTS + 1) * 64 * 2;      // 102,400,128 B (16B-aligned)
    const size_t need     = bf_bytes + (size_t)WPK_ELEMS * 2;  // + 57,344 B packed weights
    if (ws_size >= need) {
        short* bfeats = (short*)d_ws;
        short* wpk    = (short*)((char*)d_ws + bf_bytes);
        hipLaunchKernelGGL(cvt_bf16, dim3(4096), dim3(256), 0, stream, feats, bfeats);
        hipLaunchKernelGGL(pack_w, dim3((WPK_ELEMS + 1023) / 1024), dim3(1024), 0, stream,
                           W, wpk);
        hipLaunchKernelGGL(mh_conv_bf, dim3(NT / 16), dim3(1024), 0, stream,
                           bfeats, wpk, kmap, out);
    } else {
        hipLaunchKernelGGL(mh_conv_fp32, dim3(1024), dim3(512), 0, stream,
                           feats, W, kmap, out);
    }
}